// Round 5
// baseline (427.368 us; speedup 1.0000x reference)
//
#include <hip/hip_runtime.h>

// ---------------------------------------------------------------------------
// SparseMultiHeadAttention: N=32768 pts, C=512, H=8, D=64, 8^3 windows (64x512)
// Pipeline: transpose W -> gather x (window-sorted, bf16) -> QKV GEMM + fused
// RMSnorm epilogue -> windowed flash attention (barrier-free, L2-direct K/V)
// -> output GEMM (scatter rows).
// ---------------------------------------------------------------------------

typedef __attribute__((ext_vector_type(4))) float f32x4;
typedef __attribute__((ext_vector_type(8))) short s16x8;
typedef __attribute__((ext_vector_type(4))) short s16x4;

#define MFMA(a, b, c) __builtin_amdgcn_mfma_f32_16x16x32_bf16((a), (b), (c), 0, 0, 0)

__device__ __forceinline__ short f2bf(float f) {
  union { float f; unsigned u; } v; v.f = f;
  unsigned r = v.u + 0x7fffu + ((v.u >> 16) & 1u);
  return (short)(r >> 16);
}

// async global->LDS, 16B per lane; lds ptr must be wave-uniform base
__device__ __forceinline__ void gload16(const void* g, void* l) {
  __builtin_amdgcn_global_load_lds(
      (const __attribute__((address_space(1))) unsigned int*)g,
      (__attribute__((address_space(3))) unsigned int*)l, 16, 0, 0);
}

// ---------------- W transpose + bf16 convert: w[K][N] -> wt[N][K] -----------
__global__ __launch_bounds__(256) void transpose_w(const float* __restrict__ w,
                                                   short* __restrict__ wt,
                                                   int Ncols) {
  __shared__ float tile[64][65];
  const int t = threadIdx.x;
  const int ntn = Ncols >> 6;
  const int bk = blockIdx.x / ntn, bn = blockIdx.x % ntn;
  const int c = t & 63, r0 = t >> 6;
#pragma unroll
  for (int i = 0; i < 16; ++i) {
    int k = i * 4 + r0;
    tile[k][c] = w[(size_t)(bk * 64 + k) * Ncols + bn * 64 + c];
  }
  __syncthreads();
#pragma unroll
  for (int i = 0; i < 16; ++i) {
    int n = i * 4 + r0;
    wt[(size_t)(bn * 64 + n) * 512 + bk * 64 + c] = f2bf(tile[c][n]);
  }
}

// ------------- gather x into window-sorted order, fp32 -> bf16 --------------
__global__ __launch_bounds__(256) void gather_x(const float* __restrict__ x,
                                                const int* __restrict__ coords,
                                                short* __restrict__ xs,
                                                int* __restrict__ nofp) {
  const int t = threadIdx.x, lane = t & 63, wid = t >> 6;
  const int n = blockIdx.x * 4 + wid;
  const int cx = coords[n * 4 + 1], cy = coords[n * 4 + 2], cz = coords[n * 4 + 3];
  const int w = ((cx >> 3) * 4 + (cy >> 3)) * 4 + (cz >> 3);
  const int r = ((cz & 7) << 6) | ((cy & 7) << 3) | (cx & 7);
  const int p = w * 512 + r;
  const f32x4* xr = (const f32x4*)(x + (size_t)n * 512);
  f32x4 v0 = xr[lane * 2], v1 = xr[lane * 2 + 1];
  s16x8 o;
  o[0] = f2bf(v0[0]); o[1] = f2bf(v0[1]); o[2] = f2bf(v0[2]); o[3] = f2bf(v0[3]);
  o[4] = f2bf(v1[0]); o[5] = f2bf(v1[1]); o[6] = f2bf(v1[2]); o[7] = f2bf(v1[3]);
  *(s16x8*)(xs + (size_t)p * 512 + lane * 8) = o;
  if (lane == 0) nofp[p] = n;
}

// ---------------- QKV GEMM (M=32768,K=512,N=1536) + fused RMSnorm ----------
__global__ __launch_bounds__(256) void gemm_qkv(
    const short* __restrict__ xs, const short* __restrict__ wt,
    const float* __restrict__ bqkv, const float* __restrict__ gq,
    const float* __restrict__ gk, short* __restrict__ Qs,
    short* __restrict__ Ks, short* __restrict__ Vt) {
  __shared__ short As[128 * 32];
  __shared__ short Bs[128 * 32];
  const int t = threadIdx.x, lane = t & 63, wid = t >> 6;
  const int bm = blockIdx.x / 12, bn = blockIdx.x % 12;
  const int wr = wid >> 1, wc = wid & 1;
  const int rowbase = bm * 128, colbase = bn * 128;
  f32x4 acc[4][4];
#pragma unroll
  for (int m = 0; m < 4; ++m)
#pragma unroll
    for (int n = 0; n < 4; ++n) acc[m][n] = (f32x4){0.f, 0.f, 0.f, 0.f};

  const int srow = lane >> 2, sslot = lane & 3;
  for (int kt = 0; kt < 16; ++kt) {
#pragma unroll
    for (int i = 0; i < 2; ++i) {
      int row = i * 64 + wid * 16 + srow;
      int gc = sslot ^ ((row >> 2) & 3);
      gload16(xs + (size_t)(rowbase + row) * 512 + kt * 32 + gc * 8,
              &As[(i * 64 + wid * 16) * 32]);
      gload16(wt + (size_t)(colbase + row) * 512 + kt * 32 + gc * 8,
              &Bs[(i * 64 + wid * 16) * 32]);
    }
    __syncthreads();
    s16x8 af[4], bfr[4];
#pragma unroll
    for (int m = 0; m < 4; ++m) {
      int row = wr * 64 + m * 16 + (lane & 15);
      int ch = (lane >> 4) ^ ((row >> 2) & 3);
      af[m] = *(const s16x8*)&As[row * 32 + ch * 8];
    }
#pragma unroll
    for (int n = 0; n < 4; ++n) {
      int row = wc * 64 + n * 16 + (lane & 15);
      int ch = (lane >> 4) ^ ((row >> 2) & 3);
      bfr[n] = *(const s16x8*)&Bs[row * 32 + ch * 8];
    }
#pragma unroll
    for (int m = 0; m < 4; ++m)
#pragma unroll
      for (int n = 0; n < 4; ++n) acc[m][n] = MFMA(af[m], bfr[n], acc[m][n]);
    __syncthreads();
  }

  // epilogue: this wave's 64 cols are exactly one (which, head) D-group
  const int wcb = colbase + wc * 64;
  const int which = wcb >> 9;
  const int h = (wcb >> 6) & 7;
  float bias[4], gam[4];
#pragma unroll
  for (int n = 0; n < 4; ++n) {
    int d = n * 16 + (lane & 15);
    bias[n] = bqkv[wcb + d];
    gam[n] = (which == 0) ? gq[h * 64 + d] : (which == 1) ? gk[h * 64 + d] : 1.0f;
  }
#pragma unroll
  for (int m = 0; m < 4; ++m) {
#pragma unroll
    for (int n = 0; n < 4; ++n)
#pragma unroll
      for (int j = 0; j < 4; ++j) acc[m][n][j] += bias[n];
    if (which < 2) {
      float ss[4] = {0.f, 0.f, 0.f, 0.f};
#pragma unroll
      for (int n = 0; n < 4; ++n)
#pragma unroll
        for (int j = 0; j < 4; ++j) ss[j] += acc[m][n][j] * acc[m][n][j];
      float scl[4];
#pragma unroll
      for (int j = 0; j < 4; ++j) {
#pragma unroll
        for (int msk = 1; msk < 16; msk <<= 1) ss[j] += __shfl_xor(ss[j], msk, 64);
        float nrm = fmaxf(sqrtf(ss[j]), 1e-12f);
        // q: gamma*sqrt(D)/nrm * (1/sqrt(D)) = gamma/nrm ; k: gamma*8/nrm
        scl[j] = ((which == 0) ? 1.0f : 8.0f) / nrm;
      }
#pragma unroll
      for (int j = 0; j < 4; ++j) {
        int p = rowbase + wr * 64 + m * 16 + (lane >> 4) * 4 + j;
        int w = p >> 9, mm = p & 511;
#pragma unroll
        for (int n = 0; n < 4; ++n) {
          int d = n * 16 + (lane & 15);
          float v = acc[m][n][j] * gam[n] * scl[j];
          if (which == 0)
            Qs[((w * 8 + h) * 512 + mm) * 64 + d] = f2bf(v);
          else
            Ks[((w * 8 + h) * 512 + mm) * 64 + d] = f2bf(v);
        }
      }
    } else {
      // V: pack 4 consecutive-m bf16 into one 8B store (coalesced-ish scatter)
      int pb = rowbase + wr * 64 + m * 16 + (lane >> 4) * 4;
      int w = pb >> 9, mm = pb & 511;
#pragma unroll
      for (int n = 0; n < 4; ++n) {
        int d = n * 16 + (lane & 15);
        s16x4 pk;
#pragma unroll
        for (int j = 0; j < 4; ++j) pk[j] = f2bf(acc[m][n][j]);
        *(s16x4*)&Vt[((size_t)(w * 8 + h) * 64 + d) * 512 + mm] = pk;
      }
    }
  }
}

// ---------------- windowed flash attention (v2: barrier-free) --------------
// One wave owns 32 q-rows of one (window,head); K/V read directly from
// global (L2-resident, 128KB per wh); P through wave-local swizzled LDS.
// 8 K-tiles of 64 keys; online softmax w/ defer-max (T13, THR=8).
__global__ __launch_bounds__(256) void attn_k(const short* __restrict__ Qs,
                                              const short* __restrict__ Ks,
                                              const short* __restrict__ Vt,
                                              short* __restrict__ Hs) {
  __shared__ short Pl[4][32 * 64];  // per-wave slab, XOR-swizzled chunks
  const int t = threadIdx.x, lane = t & 63, wid = t >> 6;
  // XCD-aware swizzle (2048 blocks % 8 == 0 -> bijective)
  const int bid = blockIdx.x;
  const int swz = (bid & 7) * 256 + (bid >> 3);
  const int wv = swz * 4 + wid;          // 0..8191
  const int wh = wv >> 4;                // (window*8 + head), 0..511
  const int qt = wv & 15;                // 16 q-tiles of 32 rows
  const short* Qb = Qs + (size_t)wh * 512 * 64;
  const short* Kb = Ks + (size_t)wh * 512 * 64;
  const short* Vb = Vt + (size_t)wh * 64 * 512;
  short* slab = Pl[wid];

  s16x8 aq[2][2];
#pragma unroll
  for (int mi = 0; mi < 2; ++mi)
#pragma unroll
    for (int ks = 0; ks < 2; ++ks) {
      int row = qt * 32 + mi * 16 + (lane & 15);
      aq[mi][ks] = *(const s16x8*)&Qb[row * 64 + ks * 32 + (lane >> 4) * 8];
    }
  f32x4 oacc[2][4];
  float rm[2][4], rl[2][4];
#pragma unroll
  for (int mi = 0; mi < 2; ++mi) {
#pragma unroll
    for (int n = 0; n < 4; ++n) oacc[mi][n] = (f32x4){0.f, 0.f, 0.f, 0.f};
#pragma unroll
    for (int j = 0; j < 4; ++j) { rm[mi][j] = -1e30f; rl[mi][j] = 0.f; }
  }

  for (int kt = 0; kt < 8; ++kt) {
    const int kb = kt * 64;
    // ---- QK^T: B-frags straight from global (L2) ----
    f32x4 s[2][4];
#pragma unroll
    for (int mi = 0; mi < 2; ++mi)
#pragma unroll
      for (int n = 0; n < 4; ++n) s[mi][n] = (f32x4){0.f, 0.f, 0.f, 0.f};
#pragma unroll
    for (int ks = 0; ks < 2; ++ks)
#pragma unroll
      for (int n = 0; n < 4; ++n) {
        int kr = kb + n * 16 + (lane & 15);
        s16x8 bk = *(const s16x8*)&Kb[kr * 64 + ks * 32 + (lane >> 4) * 8];
        s[0][n] = MFMA(aq[0][ks], bk, s[0][n]);
        s[1][n] = MFMA(aq[1][ks], bk, s[1][n]);
      }

    // ---- online softmax (rows = (lane>>4)*4+j; reduce over lane&15 + n) ----
#pragma unroll
    for (int mi = 0; mi < 2; ++mi)
#pragma unroll
      for (int j = 0; j < 4; ++j) {
        float v = fmaxf(fmaxf(s[mi][0][j], s[mi][1][j]),
                        fmaxf(s[mi][2][j], s[mi][3][j]));
#pragma unroll
        for (int msk = 1; msk < 16; msk <<= 1) v = fmaxf(v, __shfl_xor(v, msk, 64));
        if (!__all(v - rm[mi][j] <= 8.0f)) {  // T13 defer-max
          float nm = fmaxf(rm[mi][j], v);
          float f = __expf(rm[mi][j] - nm);
          rm[mi][j] = nm;
          rl[mi][j] *= f;
#pragma unroll
          for (int n2 = 0; n2 < 4; ++n2) oacc[mi][n2][j] *= f;
        }
        float sum = 0.f;
#pragma unroll
        for (int n = 0; n < 4; ++n) {
          float pe = __expf(s[mi][n][j] - rm[mi][j]);
          s[mi][n][j] = pe;
          sum += pe;
        }
#pragma unroll
        for (int msk = 1; msk < 16; msk <<= 1) sum += __shfl_xor(sum, msk, 64);
        rl[mi][j] += sum;
      }

    // ---- P -> wave-local LDS (chunk-XOR swizzle) ----
#pragma unroll
    for (int mi = 0; mi < 2; ++mi)
#pragma unroll
      for (int n = 0; n < 4; ++n)
#pragma unroll
        for (int j = 0; j < 4; ++j) {
          int r = mi * 16 + (lane >> 4) * 4 + j;
          int col = n * 16 + (lane & 15);
          slab[r * 64 + (((col >> 3) ^ (r & 7)) << 3) + (col & 7)] =
              f2bf(s[mi][n][j]);
        }

    // ---- PV: A from LDS, B (V^T rows) straight from global ----
#pragma unroll
    for (int ks = 0; ks < 2; ++ks) {
      s16x8 ap[2];
#pragma unroll
      for (int mi = 0; mi < 2; ++mi) {
        int row = mi * 16 + (lane & 15);
        int ch = (ks * 4 + (lane >> 4)) ^ (row & 7);
        ap[mi] = *(const s16x8*)&slab[row * 64 + ch * 8];
      }
#pragma unroll
      for (int n2 = 0; n2 < 4; ++n2) {
        int dr = n2 * 16 + (lane & 15);
        s16x8 bv = *(const s16x8*)&Vb[dr * 512 + kb + ks * 32 + (lane >> 4) * 8];
        oacc[0][n2] = MFMA(ap[0], bv, oacc[0][n2]);
        oacc[1][n2] = MFMA(ap[1], bv, oacc[1][n2]);
      }
    }
  }

  const int w = wh >> 3, hh = wh & 7;
#pragma unroll
  for (int mi = 0; mi < 2; ++mi)
#pragma unroll
    for (int j = 0; j < 4; ++j) {
      float inv = 1.0f / rl[mi][j];
      int row = qt * 32 + mi * 16 + (lane >> 4) * 4 + j;
      int p = w * 512 + row;
#pragma unroll
      for (int n2 = 0; n2 < 4; ++n2) {
        int d = n2 * 16 + (lane & 15);
        Hs[(size_t)p * 512 + hh * 64 + d] = f2bf(oacc[mi][n2][j] * inv);
      }
    }
}

// ---------------- output GEMM (M=32768,K=512,N=512), scatter rows ----------
__global__ __launch_bounds__(256) void gemm_out_k(
    const short* __restrict__ Hs, const short* __restrict__ wt,
    const float* __restrict__ bout, const int* __restrict__ nofp,
    float* __restrict__ out) {
  __shared__ short As[128 * 32];
  __shared__ short Bs[128 * 32];
  const int t = threadIdx.x, lane = t & 63, wid = t >> 6;
  const int bm = blockIdx.x >> 2, bn = blockIdx.x & 3;
  const int wr = wid >> 1, wc = wid & 1;
  const int rowbase = bm * 128, colbase = bn * 128;
  f32x4 acc[4][4];
#pragma unroll
  for (int m = 0; m < 4; ++m)
#pragma unroll
    for (int n = 0; n < 4; ++n) acc[m][n] = (f32x4){0.f, 0.f, 0.f, 0.f};

  const int srow = lane >> 2, sslot = lane & 3;
  for (int kt = 0; kt < 16; ++kt) {
#pragma unroll
    for (int i = 0; i < 2; ++i) {
      int row = i * 64 + wid * 16 + srow;
      int gc = sslot ^ ((row >> 2) & 3);
      gload16(Hs + (size_t)(rowbase + row) * 512 + kt * 32 + gc * 8,
              &As[(i * 64 + wid * 16) * 32]);
      gload16(wt + (size_t)(colbase + row) * 512 + kt * 32 + gc * 8,
              &Bs[(i * 64 + wid * 16) * 32]);
    }
    __syncthreads();
    s16x8 af[4], bfr[4];
#pragma unroll
    for (int m = 0; m < 4; ++m) {
      int row = wr * 64 + m * 16 + (lane & 15);
      int ch = (lane >> 4) ^ ((row >> 2) & 3);
      af[m] = *(const s16x8*)&As[row * 32 + ch * 8];
    }
#pragma unroll
    for (int n = 0; n < 4; ++n) {
      int row = wc * 64 + n * 16 + (lane & 15);
      int ch = (lane >> 4) ^ ((row >> 2) & 3);
      bfr[n] = *(const s16x8*)&Bs[row * 32 + ch * 8];
    }
#pragma unroll
    for (int m = 0; m < 4; ++m)
#pragma unroll
      for (int n = 0; n < 4; ++n) acc[m][n] = MFMA(af[m], bfr[n], acc[m][n]);
    __syncthreads();
  }
#pragma unroll
  for (int m = 0; m < 4; ++m)
#pragma unroll
    for (int j = 0; j < 4; ++j) {
      int p = rowbase + wr * 64 + m * 16 + (lane >> 4) * 4 + j;
      int norig = nofp[p];
#pragma unroll
      for (int n = 0; n < 4; ++n) {
        int c = colbase + wc * 64 + n * 16 + (lane & 15);
        out[(size_t)norig * 512 + c] = acc[m][n][j] + bout[c];
      }
    }
}

// ---------------------------------------------------------------------------
extern "C" void kernel_launch(void* const* d_in, const int* in_sizes, int n_in,
                              void* d_out, int out_size, void* d_ws,
                              size_t ws_size, hipStream_t stream) {
  const float* x      = (const float*)d_in[0];
  const int*   coords = (const int*)d_in[1];
  const float* wqkv   = (const float*)d_in[2];
  const float* bqkv   = (const float*)d_in[3];
  const float* gq     = (const float*)d_in[4];
  const float* gk     = (const float*)d_in[5];
  const float* wout   = (const float*)d_in[6];
  const float* bout   = (const float*)d_in[7];
  float* out = (float*)d_out;
  char* ws = (char*)d_ws;

  short* xs    = (short*)(ws + 0);            // 32 MB  [32768][512] bf16 sorted
  short* wqkvt = (short*)(ws + 33554432);     // 1.5 MB [1536][512] bf16
  short* woutt = (short*)(ws + 35127296);     // 0.5 MB [512][512]  bf16
  short* Qs    = (short*)(ws + 35651584);     // 32 MB  [wh][512][64]
  short* Ks    = (short*)(ws + 69206016);     // 32 MB  [wh][512][64]
  short* Vt    = (short*)(ws + 102760448);    // 32 MB  [wh][64][512]
  short* Hs    = (short*)(ws + 136314880);    // 32 MB  [32768][512]
  int*   nofp  = (int*)(ws + 169869312);      // 128 KB

  transpose_w<<<dim3(192), dim3(256), 0, stream>>>(wqkv, wqkvt, 1536);
  transpose_w<<<dim3(64), dim3(256), 0, stream>>>(wout, woutt, 512);
  gather_x<<<dim3(8192), dim3(256), 0, stream>>>(x, coords, xs, nofp);
  gemm_qkv<<<dim3(3072), dim3(256), 0, stream>>>(xs, wqkvt, bqkv, gq, gk, Qs, Ks, Vt);
  attn_k<<<dim3(2048), dim3(256), 0, stream>>>(Qs, Ks, Vt, Hs);
  gemm_out_k<<<dim3(1024), dim3(256), 0, stream>>>(Hs, woutt, bout, nofp, out);
}

// Round 6
// 379.000 us; speedup vs baseline: 1.1276x; 1.1276x over previous
//
#include <hip/hip_runtime.h>

// ---------------------------------------------------------------------------
// SparseMultiHeadAttention: N=32768 pts, C=512, H=8, D=64, 8^3 windows (64x512)
// transpose W -> gather x (window-sorted bf16) -> QKV GEMM + fused RMSnorm ->
// windowed attention v3 (swapped-QK^T 32x32 MFMA, in-register softmax, zero
// LDS, L2-direct K/V) -> output GEMM (scatter rows).
// ---------------------------------------------------------------------------

typedef __attribute__((ext_vector_type(4))) float f32x4;
typedef __attribute__((ext_vector_type(16))) float f32x16;
typedef __attribute__((ext_vector_type(8))) short s16x8;
typedef __attribute__((ext_vector_type(4))) short s16x4;
typedef __attribute__((ext_vector_type(4))) int i32x4;

#define MFMA(a, b, c) __builtin_amdgcn_mfma_f32_16x16x32_bf16((a), (b), (c), 0, 0, 0)
#define MFMA32(a, b, c) __builtin_amdgcn_mfma_f32_32x32x16_bf16((a), (b), (c), 0, 0, 0)

__device__ __forceinline__ short f2bf(float f) {
  union { float f; unsigned u; } v; v.f = f;
  unsigned r = v.u + 0x7fffu + ((v.u >> 16) & 1u);
  return (short)(r >> 16);
}

// pack two f32 -> one dword of 2 bf16 (lo=a, hi=b), RNE
__device__ __forceinline__ int cvtpk(float a, float b) {
  int r;
  asm("v_cvt_pk_bf16_f32 %0, %1, %2" : "=v"(r) : "v"(a), "v"(b));
  return r;
}

// async global->LDS, 16B per lane; lds ptr must be wave-uniform base
__device__ __forceinline__ void gload16(const void* g, void* l) {
  __builtin_amdgcn_global_load_lds(
      (const __attribute__((address_space(1))) unsigned int*)g,
      (__attribute__((address_space(3))) unsigned int*)l, 16, 0, 0);
}

// ---------------- W transpose + bf16 convert: w[K][N] -> wt[N][K] -----------
__global__ __launch_bounds__(256) void transpose_w(const float* __restrict__ w,
                                                   short* __restrict__ wt,
                                                   int Ncols) {
  __shared__ float tile[64][65];
  const int t = threadIdx.x;
  const int ntn = Ncols >> 6;
  const int bk = blockIdx.x / ntn, bn = blockIdx.x % ntn;
  const int c = t & 63, r0 = t >> 6;
#pragma unroll
  for (int i = 0; i < 16; ++i) {
    int k = i * 4 + r0;
    tile[k][c] = w[(size_t)(bk * 64 + k) * Ncols + bn * 64 + c];
  }
  __syncthreads();
#pragma unroll
  for (int i = 0; i < 16; ++i) {
    int n = i * 4 + r0;
    wt[(size_t)(bn * 64 + n) * 512 + bk * 64 + c] = f2bf(tile[c][n]);
  }
}

// ------------- gather x into window-sorted order, fp32 -> bf16 --------------
__global__ __launch_bounds__(256) void gather_x(const float* __restrict__ x,
                                                const int* __restrict__ coords,
                                                short* __restrict__ xs,
                                                int* __restrict__ nofp) {
  const int t = threadIdx.x, lane = t & 63, wid = t >> 6;
  const int n = blockIdx.x * 4 + wid;
  const int cx = coords[n * 4 + 1], cy = coords[n * 4 + 2], cz = coords[n * 4 + 3];
  const int w = ((cx >> 3) * 4 + (cy >> 3)) * 4 + (cz >> 3);
  const int r = ((cz & 7) << 6) | ((cy & 7) << 3) | (cx & 7);
  const int p = w * 512 + r;
  const f32x4* xr = (const f32x4*)(x + (size_t)n * 512);
  f32x4 v0 = xr[lane * 2], v1 = xr[lane * 2 + 1];
  s16x8 o;
  o[0] = f2bf(v0[0]); o[1] = f2bf(v0[1]); o[2] = f2bf(v0[2]); o[3] = f2bf(v0[3]);
  o[4] = f2bf(v1[0]); o[5] = f2bf(v1[1]); o[6] = f2bf(v1[2]); o[7] = f2bf(v1[3]);
  *(s16x8*)(xs + (size_t)p * 512 + lane * 8) = o;
  if (lane == 0) nofp[p] = n;
}

// ---------------- QKV GEMM (M=32768,K=512,N=1536) + fused RMSnorm ----------
__global__ __launch_bounds__(256) void gemm_qkv(
    const short* __restrict__ xs, const short* __restrict__ wt,
    const float* __restrict__ bqkv, const float* __restrict__ gq,
    const float* __restrict__ gk, short* __restrict__ Qs,
    short* __restrict__ Ks, short* __restrict__ Vt) {
  __shared__ short As[128 * 32];
  __shared__ short Bs[128 * 32];
  const int t = threadIdx.x, lane = t & 63, wid = t >> 6;
  const int bm = blockIdx.x / 12, bn = blockIdx.x % 12;
  const int wr = wid >> 1, wc = wid & 1;
  const int rowbase = bm * 128, colbase = bn * 128;
  f32x4 acc[4][4];
#pragma unroll
  for (int m = 0; m < 4; ++m)
#pragma unroll
    for (int n = 0; n < 4; ++n) acc[m][n] = (f32x4){0.f, 0.f, 0.f, 0.f};

  const int srow = lane >> 2, sslot = lane & 3;
  for (int kt = 0; kt < 16; ++kt) {
#pragma unroll
    for (int i = 0; i < 2; ++i) {
      int row = i * 64 + wid * 16 + srow;
      int gc = sslot ^ ((row >> 2) & 3);
      gload16(xs + (size_t)(rowbase + row) * 512 + kt * 32 + gc * 8,
              &As[(i * 64 + wid * 16) * 32]);
      gload16(wt + (size_t)(colbase + row) * 512 + kt * 32 + gc * 8,
              &Bs[(i * 64 + wid * 16) * 32]);
    }
    __syncthreads();
    s16x8 af[4], bfr[4];
#pragma unroll
    for (int m = 0; m < 4; ++m) {
      int row = wr * 64 + m * 16 + (lane & 15);
      int ch = (lane >> 4) ^ ((row >> 2) & 3);
      af[m] = *(const s16x8*)&As[row * 32 + ch * 8];
    }
#pragma unroll
    for (int n = 0; n < 4; ++n) {
      int row = wc * 64 + n * 16 + (lane & 15);
      int ch = (lane >> 4) ^ ((row >> 2) & 3);
      bfr[n] = *(const s16x8*)&Bs[row * 32 + ch * 8];
    }
#pragma unroll
    for (int m = 0; m < 4; ++m)
#pragma unroll
      for (int n = 0; n < 4; ++n) acc[m][n] = MFMA(af[m], bfr[n], acc[m][n]);
    __syncthreads();
  }

  // epilogue: this wave's 64 cols are exactly one (which, head) D-group
  const int wcb = colbase + wc * 64;
  const int which = wcb >> 9;
  const int h = (wcb >> 6) & 7;
  float bias[4], gam[4];
#pragma unroll
  for (int n = 0; n < 4; ++n) {
    int d = n * 16 + (lane & 15);
    bias[n] = bqkv[wcb + d];
    gam[n] = (which == 0) ? gq[h * 64 + d] : (which == 1) ? gk[h * 64 + d] : 1.0f;
  }
#pragma unroll
  for (int m = 0; m < 4; ++m) {
#pragma unroll
    for (int n = 0; n < 4; ++n)
#pragma unroll
      for (int j = 0; j < 4; ++j) acc[m][n][j] += bias[n];
    if (which < 2) {
      float ss[4] = {0.f, 0.f, 0.f, 0.f};
#pragma unroll
      for (int n = 0; n < 4; ++n)
#pragma unroll
        for (int j = 0; j < 4; ++j) ss[j] += acc[m][n][j] * acc[m][n][j];
      float scl[4];
#pragma unroll
      for (int j = 0; j < 4; ++j) {
#pragma unroll
        for (int msk = 1; msk < 16; msk <<= 1) ss[j] += __shfl_xor(ss[j], msk, 64);
        float nrm = fmaxf(sqrtf(ss[j]), 1e-12f);
        // q: gamma*sqrt(D)/nrm * (1/sqrt(D)) = gamma/nrm ; k: gamma*8/nrm
        scl[j] = ((which == 0) ? 1.0f : 8.0f) / nrm;
      }
#pragma unroll
      for (int j = 0; j < 4; ++j) {
        int p = rowbase + wr * 64 + m * 16 + (lane >> 4) * 4 + j;
        int w = p >> 9, mm = p & 511;
#pragma unroll
        for (int n = 0; n < 4; ++n) {
          int d = n * 16 + (lane & 15);
          float v = acc[m][n][j] * gam[n] * scl[j];
          if (which == 0)
            Qs[((w * 8 + h) * 512 + mm) * 64 + d] = f2bf(v);
          else
            Ks[((w * 8 + h) * 512 + mm) * 64 + d] = f2bf(v);
        }
      }
    } else {
      // V: pack 4 consecutive-m bf16 into one 8B store (coalesced-ish scatter)
      int pb = rowbase + wr * 64 + m * 16 + (lane >> 4) * 4;
      int w = pb >> 9, mm = pb & 511;
#pragma unroll
      for (int n = 0; n < 4; ++n) {
        int d = n * 16 + (lane & 15);
        s16x4 pk;
#pragma unroll
        for (int j = 0; j < 4; ++j) pk[j] = f2bf(acc[m][n][j]);
        *(s16x4*)&Vt[((size_t)(w * 8 + h) * 64 + d) * 512 + mm] = pk;
      }
    }
  }
}

// ------------- windowed attention v3: swapped-QK^T, in-register softmax -----
// One wave = 32 q-rows of one (window,head). S^T = mfma32(K,Q) puts a full
// 32-key slice lane-local for q=lane&31; softmax is a register tree + one
// shfl_xor(32). P->bf16 via cvt_pk, redistributed to the PV B-fragment with
// shfl_xor(32)+select. PV computes O^T = mfma32(V^T, P) so the accumulator,
// m, l all stay keyed to q=lane&31. No LDS, no barriers.
__global__ __launch_bounds__(256) void attn_k(const short* __restrict__ Qs,
                                              const short* __restrict__ Ks,
                                              const short* __restrict__ Vt,
                                              short* __restrict__ Hs) {
  const int t = threadIdx.x, lane = t & 63, wid = t >> 6;
  const int lo = lane & 31, hi = lane >> 5;
  // XCD-aware swizzle (2048 % 8 == 0 -> bijective); 4 blocks/wh per XCD chunk
  const int bid = blockIdx.x;
  const int swz = (bid & 7) * 256 + (bid >> 3);
  const int wv = swz * 4 + wid;          // 0..8191
  const int wh = wv >> 4;                // (window*8 + head), 0..511
  const int qbase = (wv & 15) * 32;      // 16 q-tiles of 32 rows
  const short* Qb = Qs + (size_t)wh * 512 * 64;
  const short* Kb = Ks + (size_t)wh * 512 * 64;
  const short* Vb = Vt + (size_t)wh * 64 * 512;

  s16x8 qf[4];
#pragma unroll
  for (int j = 0; j < 4; ++j)
    qf[j] = *(const s16x8*)&Qb[(qbase + lo) * 64 + j * 16 + hi * 8];

  f32x16 oacc0, oacc1;
#pragma unroll
  for (int c = 0; c < 16; ++c) { oacc0[c] = 0.f; oacc1[c] = 0.f; }
  float m = -1e30f, l = 0.f;

  for (int kt = 0; kt < 16; ++kt) {
    const int kb = kt * 32;
    // K-frags (A-operand rows = keys)
    s16x8 kf0 = *(const s16x8*)&Kb[(kb + lo) * 64 + 0 + hi * 8];
    s16x8 kf1 = *(const s16x8*)&Kb[(kb + lo) * 64 + 16 + hi * 8];
    s16x8 kf2 = *(const s16x8*)&Kb[(kb + lo) * 64 + 32 + hi * 8];
    s16x8 kf3 = *(const s16x8*)&Kb[(kb + lo) * 64 + 48 + hi * 8];
    f32x16 sc;
#pragma unroll
    for (int c = 0; c < 16; ++c) sc[c] = 0.f;
    sc = MFMA32(kf0, qf[0], sc);
    sc = MFMA32(kf1, qf[1], sc);
    sc = MFMA32(kf2, qf[2], sc);
    sc = MFMA32(kf3, qf[3], sc);
    // V^T-frags issued early: L2 latency hides under softmax VALU
    s16x8 vf00 = *(const s16x8*)&Vb[(lo)*512 + kb + 0 + hi * 8];
    s16x8 vf10 = *(const s16x8*)&Vb[(32 + lo) * 512 + kb + 0 + hi * 8];
    s16x8 vf01 = *(const s16x8*)&Vb[(lo)*512 + kb + 16 + hi * 8];
    s16x8 vf11 = *(const s16x8*)&Vb[(32 + lo) * 512 + kb + 16 + hi * 8];

    // ---- in-register online softmax (q = lane&31 for every value) ----
    float mx;
    {
      float t1 = fmaxf(fmaxf(sc[0], sc[1]), fmaxf(sc[2], sc[3]));
      float t2 = fmaxf(fmaxf(sc[4], sc[5]), fmaxf(sc[6], sc[7]));
      float t3 = fmaxf(fmaxf(sc[8], sc[9]), fmaxf(sc[10], sc[11]));
      float t4 = fmaxf(fmaxf(sc[12], sc[13]), fmaxf(sc[14], sc[15]));
      mx = fmaxf(fmaxf(t1, t2), fmaxf(t3, t4));
    }
    mx = fmaxf(mx, __shfl_xor(mx, 32, 64));
    if (!__all(mx - m <= 8.0f)) {  // T13 defer-max
      float nm = fmaxf(m, mx);
      float f = __expf(m - nm);
      m = nm; l *= f;
#pragma unroll
      for (int c = 0; c < 16; ++c) { oacc0[c] *= f; oacc1[c] *= f; }
    }
    float p[16];
#pragma unroll
    for (int c = 0; c < 16; ++c) p[c] = __expf(sc[c] - m);
    float sum = ((p[0] + p[1]) + (p[2] + p[3])) + ((p[4] + p[5]) + (p[6] + p[7])) +
                (((p[8] + p[9]) + (p[10] + p[11])) + ((p[12] + p[13]) + (p[14] + p[15])));
    sum += __shfl_xor(sum, 32, 64);
    l += sum;

    // ---- P -> bf16 PV B-fragments (keys 0-15 and 16-31), in-register ----
    // lane's p[c] = P[key=(c&3)+8*(c>>2)+4*hi][q=lo]
    int a0 = cvtpk(p[0], p[1]), a1 = cvtpk(p[2], p[3]);
    int b0 = cvtpk(p[4], p[5]), b1 = cvtpk(p[6], p[7]);
    int c0 = cvtpk(p[8], p[9]), c1 = cvtpk(p[10], p[11]);
    int d0 = cvtpk(p[12], p[13]), d1 = cvtpk(p[14], p[15]);
    int xa0 = __shfl_xor(a0, 32, 64), xa1 = __shfl_xor(a1, 32, 64);
    int xb0 = __shfl_xor(b0, 32, 64), xb1 = __shfl_xor(b1, 32, 64);
    int xc0 = __shfl_xor(c0, 32, 64), xc1 = __shfl_xor(c1, 32, 64);
    int xd0 = __shfl_xor(d0, 32, 64), xd1 = __shfl_xor(d1, 32, 64);
    union { i32x4 i; s16x8 s; } f0u, f1u;
    f0u.i = hi ? (i32x4){xb0, xb1, b0, b1} : (i32x4){a0, a1, xa0, xa1};
    f1u.i = hi ? (i32x4){xd0, xd1, d0, d1} : (i32x4){c0, c1, xc0, xc1};

    // ---- PV: O^T += V^T-frag (A) x P-frag (B) ----
    oacc0 = MFMA32(vf00, f0u.s, oacc0);
    oacc1 = MFMA32(vf10, f0u.s, oacc1);
    oacc0 = MFMA32(vf01, f1u.s, oacc0);
    oacc1 = MFMA32(vf11, f1u.s, oacc1);
  }

  const float inv = 1.0f / l;
  const int w = wh >> 3, hh = wh & 7;
  const size_t prow = (size_t)(w * 512 + qbase + lo) * 512 + hh * 64;
#pragma unroll
  for (int g = 0; g < 4; ++g) {
    s16x4 o0, o1;
#pragma unroll
    for (int j = 0; j < 4; ++j) {
      o0[j] = f2bf(oacc0[g * 4 + j] * inv);
      o1[j] = f2bf(oacc1[g * 4 + j] * inv);
    }
    *(s16x4*)&Hs[prow + g * 8 + hi * 4] = o0;
    *(s16x4*)&Hs[prow + 32 + g * 8 + hi * 4] = o1;
  }
}

// ---------------- output GEMM (M=32768,K=512,N=512), scatter rows ----------
__global__ __launch_bounds__(256) void gemm_out_k(
    const short* __restrict__ Hs, const short* __restrict__ wt,
    const float* __restrict__ bout, const int* __restrict__ nofp,
    float* __restrict__ out) {
  __shared__ short As[128 * 32];
  __shared__ short Bs[128 * 32];
  const int t = threadIdx.x, lane = t & 63, wid = t >> 6;
  const int bm = blockIdx.x >> 2, bn = blockIdx.x & 3;
  const int wr = wid >> 1, wc = wid & 1;
  const int rowbase = bm * 128, colbase = bn * 128;
  f32x4 acc[4][4];
#pragma unroll
  for (int m = 0; m < 4; ++m)
#pragma unroll
    for (int n = 0; n < 4; ++n) acc[m][n] = (f32x4){0.f, 0.f, 0.f, 0.f};

  const int srow = lane >> 2, sslot = lane & 3;
  for (int kt = 0; kt < 16; ++kt) {
#pragma unroll
    for (int i = 0; i < 2; ++i) {
      int row = i * 64 + wid * 16 + srow;
      int gc = sslot ^ ((row >> 2) & 3);
      gload16(Hs + (size_t)(rowbase + row) * 512 + kt * 32 + gc * 8,
              &As[(i * 64 + wid * 16) * 32]);
      gload16(wt + (size_t)(colbase + row) * 512 + kt * 32 + gc * 8,
              &Bs[(i * 64 + wid * 16) * 32]);
    }
    __syncthreads();
    s16x8 af[4], bfr[4];
#pragma unroll
    for (int m = 0; m < 4; ++m) {
      int row = wr * 64 + m * 16 + (lane & 15);
      int ch = (lane >> 4) ^ ((row >> 2) & 3);
      af[m] = *(const s16x8*)&As[row * 32 + ch * 8];
    }
#pragma unroll
    for (int n = 0; n < 4; ++n) {
      int row = wc * 64 + n * 16 + (lane & 15);
      int ch = (lane >> 4) ^ ((row >> 2) & 3);
      bfr[n] = *(const s16x8*)&Bs[row * 32 + ch * 8];
    }
#pragma unroll
    for (int m = 0; m < 4; ++m)
#pragma unroll
      for (int n = 0; n < 4; ++n) acc[m][n] = MFMA(af[m], bfr[n], acc[m][n]);
    __syncthreads();
  }
#pragma unroll
  for (int m = 0; m < 4; ++m)
#pragma unroll
    for (int j = 0; j < 4; ++j) {
      int p = rowbase + wr * 64 + m * 16 + (lane >> 4) * 4 + j;
      int norig = nofp[p];
#pragma unroll
      for (int n = 0; n < 4; ++n) {
        int c = colbase + wc * 64 + n * 16 + (lane & 15);
        out[(size_t)norig * 512 + c] = acc[m][n][j] + bout[c];
      }
    }
}

// ---------------------------------------------------------------------------
extern "C" void kernel_launch(void* const* d_in, const int* in_sizes, int n_in,
                              void* d_out, int out_size, void* d_ws,
                              size_t ws_size, hipStream_t stream) {
  const float* x      = (const float*)d_in[0];
  const int*   coords = (const int*)d_in[1];
  const float* wqkv   = (const float*)d_in[2];
  const float* bqkv   = (const float*)d_in[3];
  const float* gq     = (const float*)d_in[4];
  const float* gk     = (const float*)d_in[5];
  const float* wout   = (const float*)d_in[6];
  const float* bout   = (const float*)d_in[7];
  float* out = (float*)d_out;
  char* ws = (char*)d_ws;

  short* xs    = (short*)(ws + 0);            // 32 MB  [32768][512] bf16 sorted
  short* wqkvt = (short*)(ws + 33554432);     // 1.5 MB [1536][512] bf16
  short* woutt = (short*)(ws + 35127296);     // 0.5 MB [512][512]  bf16
  short* Qs    = (short*)(ws + 35651584);     // 32 MB  [wh][512][64]
  short* Ks    = (short*)(ws + 69206016);     // 32 MB  [wh][512][64]
  short* Vt    = (short*)(ws + 102760448);    // 32 MB  [wh][64][512]
  short* Hs    = (short*)(ws + 136314880);    // 32 MB  [32768][512]
  int*   nofp  = (int*)(ws + 169869312);      // 128 KB

  transpose_w<<<dim3(192), dim3(256), 0, stream>>>(wqkv, wqkvt, 1536);
  transpose_w<<<dim3(64), dim3(256), 0, stream>>>(wout, woutt, 512);
  gather_x<<<dim3(8192), dim3(256), 0, stream>>>(x, coords, xs, nofp);
  gemm_qkv<<<dim3(3072), dim3(256), 0, stream>>>(xs, wqkvt, bqkv, gq, gk, Qs, Ks, Vt);
  attn_k<<<dim3(2048), dim3(256), 0, stream>>>(Qs, Ks, Vt, Hs);
  gemm_out_k<<<dim3(1024), dim3(256), 0, stream>>>(Hs, woutt, bout, nofp, out);
}